// Round 6
// baseline (129.571 us; speedup 1.0000x reference)
//
#include <hip/hip_runtime.h>
#include <math.h>

// B=16, C=256, H=W=64, r=16.
// dct = (1/4096) * D @ X @ D^T per (b,c) slice, D[u,h] = cos(pi*u*(2h+1)/128)
// Y' = D @ X^T @ D^T = (D @ X @ D^T)^T  -- same max, no LDS transpose.
//
// v6 = three kernels, cross-block dataflow ONLY via kernel boundaries
// (two in-kernel cross-block attempts both raced; kernel boundary is the
// only visibility mechanism used from here on).
// k1: round-0 verified dct+max, byte-identical (1024 blocks x 4 slices).
// k2: 16 blocks (one per batch): round-0's verified MLP math computes
//     weights[4096] once (removes 2048 redundant MLPs from the stream kernel).
// k3: pure stream: NO LDS, NO barriers -> no vmcnt(0)-before-s_barrier drain;
//     scalar weight loads (uniform -> s_load path) + bulk loads + incremental
//     counted-vmcnt stores = full read/write overlap.

#define S 72  // ushort stride: 144 B rows (16B-aligned b128, bank-spread)

typedef __attribute__((ext_vector_type(8))) short bf16x8;
typedef __attribute__((ext_vector_type(4))) float f32x4;

__device__ inline unsigned short f2bf(float x) {
    union { float f; unsigned u; } v; v.f = x;
    unsigned r = v.u + 0x7FFF + ((v.u >> 16) & 1);
    return (unsigned short)(r >> 16);
}

__global__ __launch_bounds__(256, 4) void dct_max_kernel(const float* __restrict__ ip,
                                                         float* __restrict__ top1) {
    __shared__ unsigned short Dbf[64 * S];  // D[u][h]
    __shared__ unsigned short Xbf[64 * S];  // X[h][w]
    __shared__ unsigned short Tbf[64 * S];  // T[u][w]
    __shared__ float red[4];

    const int t = threadIdx.x;

#pragma unroll
    for (int i = 0; i < 16; ++i) {
        int idx = i * 256 + t;
        int u = idx >> 6, h = idx & 63;
        int mm = (u * (2 * h + 1)) & 255;
        Dbf[u * S + h] = f2bf(cospif((float)mm * (1.0f / 128.0f)));
    }

    const int wv = t >> 6;
    const int l = t & 63;
    const int m = l & 15;
    const int q = l >> 4;
    const int arow = (16 * wv + m) * S + 8 * q;
    const int xh = t >> 4;
    const int xw0 = (4 * t) & 63;

    const int bc0 = blockIdx.x * 4;
    const float4* src4 = (const float4*)(ip + (size_t)bc0 * 4096);

    float4 xv[4];
#pragma unroll
    for (int i = 0; i < 4; ++i) xv[i] = src4[i * 256 + t];

    __syncthreads();  // D ready
    const bf16x8 da0 = *(const bf16x8*)&Dbf[arow];
    const bf16x8 da1 = *(const bf16x8*)&Dbf[arow + 32];

    for (int s = 0; s < 4; ++s) {
#pragma unroll
        for (int i = 0; i < 4; ++i) {
            ushort4 p;
            p.x = f2bf(xv[i].x); p.y = f2bf(xv[i].y);
            p.z = f2bf(xv[i].z); p.w = f2bf(xv[i].w);
            *(ushort4*)&Xbf[(16 * i + xh) * S + xw0] = p;
        }
        __syncthreads();  // X visible

        if (s < 3) {
            const float4* nsrc = src4 + (size_t)(s + 1) * 1024;
#pragma unroll
            for (int i = 0; i < 4; ++i) xv[i] = nsrc[i * 256 + t];
        }

        // Stage A: T = D @ X^T
        f32x4 acc[4];
#pragma unroll
        for (int tn = 0; tn < 4; ++tn) {
            const int brow = (16 * tn + m) * S + 8 * q;
            bf16x8 b0 = *(const bf16x8*)&Xbf[brow];
            bf16x8 b1 = *(const bf16x8*)&Xbf[brow + 32];
            f32x4 c = {0.0f, 0.0f, 0.0f, 0.0f};
            c = __builtin_amdgcn_mfma_f32_16x16x32_bf16(da0, b0, c, 0, 0, 0);
            c = __builtin_amdgcn_mfma_f32_16x16x32_bf16(da1, b1, c, 0, 0, 0);
            acc[tn] = c;
        }
#pragma unroll
        for (int tn = 0; tn < 4; ++tn)
#pragma unroll
            for (int reg = 0; reg < 4; ++reg)
                Tbf[(16 * wv + 4 * q + reg) * S + 16 * tn + m] = f2bf(acc[tn][reg]);
        __syncthreads();  // T visible

        // Stage B: Y' = T @ D^T, fused max
        bf16x8 ta0 = *(const bf16x8*)&Tbf[arow];
        bf16x8 ta1 = *(const bf16x8*)&Tbf[arow + 32];
        float mx = -3.4e38f;
#pragma unroll
        for (int tn = 0; tn < 4; ++tn) {
            const int brow = (16 * tn + m) * S + 8 * q;
            bf16x8 b0 = *(const bf16x8*)&Dbf[brow];
            bf16x8 b1 = *(const bf16x8*)&Dbf[brow + 32];
            f32x4 c = {0.0f, 0.0f, 0.0f, 0.0f};
            c = __builtin_amdgcn_mfma_f32_16x16x32_bf16(ta0, b0, c, 0, 0, 0);
            c = __builtin_amdgcn_mfma_f32_16x16x32_bf16(ta1, b1, c, 0, 0, 0);
            mx = fmaxf(mx, fmaxf(fmaxf(c[0], c[1]), fmaxf(c[2], c[3])));
        }

#pragma unroll
        for (int off = 32; off > 0; off >>= 1) mx = fmaxf(mx, __shfl_down(mx, off, 64));
        if (l == 0) red[wv] = mx;
        __syncthreads();
        if (t == 0) {
            float M = fmaxf(fmaxf(red[0], red[1]), fmaxf(red[2], red[3]));
            top1[bc0 + s] = M * (1.0f / 4096.0f);
        }
    }
}

// One block per batch: weights[b*256+c] = sigmoid(relu(top1_b @ w1) @ w2)[c].
// Round-0's verified MLP layer-1 (16x16-lane reduce), then per-thread layer 2.
// Intra-block barriers only; cross-kernel visibility via launch boundary.
__global__ __launch_bounds__(256, 4) void mlp_kernel(const float* __restrict__ top1,
                                                     const float* __restrict__ w1,
                                                     const float* __restrict__ w2,
                                                     float* __restrict__ weights) {
    __shared__ float h_s[16];
    const int t = threadIdx.x;
    const int b = blockIdx.x;

    const int j = t >> 4, i = t & 15;
    float partial = 0.0f;
#pragma unroll
    for (int k = 0; k < 16; ++k) {
        int cc = i + 16 * k;
        partial = fmaf(top1[b * 256 + cc], w1[cc * 16 + j], partial);
    }
#pragma unroll
    for (int off = 8; off > 0; off >>= 1) partial += __shfl_xor(partial, off, 16);
    if (i == 0) h_s[j] = fmaxf(partial, 0.0f);
    __syncthreads();

    float p2 = 0.0f;
#pragma unroll
    for (int jj = 0; jj < 16; ++jj) p2 = fmaf(h_s[jj], w2[jj * 256 + t], p2);
    weights[b * 256 + t] = 1.0f / (1.0f + __expf(-p2));
}

// Pure stream: no LDS, no barriers. Uniform weight loads (s_load path) issued
// first; 8 bulk loads; multiply + nontemporal store with incremental vmcnt.
__global__ __launch_bounds__(256, 4) void scale_kernel(const float* __restrict__ ip,
                                                       const float* __restrict__ weights,
                                                       float* __restrict__ out) {
    const int t = threadIdx.x;
    const int bc0 = blockIdx.x * 2;

    const float w0 = weights[bc0];
    const float w1v = weights[bc0 + 1];

    const f32x4* ip4 = (const f32x4*)ip + (size_t)bc0 * 1024;
    f32x4* out4 = (f32x4*)out + (size_t)bc0 * 1024;

    f32x4 v[8];
#pragma unroll
    for (int s = 0; s < 2; ++s)
#pragma unroll
        for (int k = 0; k < 4; ++k) v[s * 4 + k] = ip4[(size_t)s * 1024 + k * 256 + t];

#pragma unroll
    for (int s = 0; s < 2; ++s) {
        const float wt = (s == 0) ? w0 : w1v;
#pragma unroll
        for (int k = 0; k < 4; ++k) {
            f32x4 r = v[s * 4 + k] * wt;
            __builtin_nontemporal_store(r, &out4[(size_t)s * 1024 + k * 256 + t]);
        }
    }
}

extern "C" void kernel_launch(void* const* d_in, const int* in_sizes, int n_in,
                              void* d_out, int out_size, void* d_ws, size_t ws_size,
                              hipStream_t stream) {
    const float* ip = (const float*)d_in[0];   // [16,256,64,64]
    const float* w1 = (const float*)d_in[1];   // [256,16]
    const float* w2 = (const float*)d_in[2];   // [16,256]
    float* out = (float*)d_out;
    float* top1 = (float*)d_ws;                // 4096 floats
    float* weights = (float*)d_ws + 4096;      // 4096 floats

    dct_max_kernel<<<1024, 256, 0, stream>>>(ip, top1);
    mlp_kernel<<<16, 256, 0, stream>>>(top1, w1, w2, weights);
    scale_kernel<<<2048, 256, 0, stream>>>(ip, weights, out);
}

// Round 7
// 126.852 us; speedup vs baseline: 1.0214x; 1.0214x over previous
//
#include <hip/hip_runtime.h>
#include <math.h>

// B=16, C=256, H=W=64, r=16.
// dct = (1/4096) * D @ X @ D^T per (b,c) slice, D[u,h] = cos(pi*u*(2h+1)/128)
// Y' = D @ X^T @ D^T = (D @ X @ D^T)^T  -- same max, no LDS transpose.
// k1: 1024 blocks x 4 slices: MFMA DCT + fused max -> top1[4096]
// k2: 1024 blocks x 4 slices: bulk ip loads issued first, tiny MLP computed
//     under their shadow, scale + nontemporal store (no RFO traffic).
//
// v7 == v0 (best measured: 127.3 us). Session A/B ledger: slice-split
// {4,2,1}/block = {127.3, 128.3, 144.9}; barrier-free k3 + separate MLP
// kernel = 129.6; in-kernel cross-block fusion raced twice (v3, v5).
// Both kernels sit near their HBM floors (k1: 64MB cold read ~10us floor;
// k2: 64MB L3-resident read + 64MB HBM write ~10-12us floor); residual
// ~100us is harness fill/launch overhead. This is the closing revert.

#define S 72  // ushort stride: 144 B rows (16B-aligned b128, bank-spread)

typedef __attribute__((ext_vector_type(8))) short bf16x8;
typedef __attribute__((ext_vector_type(4))) float f32x4;

__device__ inline unsigned short f2bf(float x) {
    union { float f; unsigned u; } v; v.f = x;
    unsigned r = v.u + 0x7FFF + ((v.u >> 16) & 1);
    return (unsigned short)(r >> 16);
}

__global__ __launch_bounds__(256, 4) void dct_max_kernel(const float* __restrict__ ip,
                                                         float* __restrict__ top1) {
    __shared__ unsigned short Dbf[64 * S];  // D[u][h]
    __shared__ unsigned short Xbf[64 * S];  // X[h][w]
    __shared__ unsigned short Tbf[64 * S];  // T[u][w]
    __shared__ float red[4];

    const int t = threadIdx.x;

#pragma unroll
    for (int i = 0; i < 16; ++i) {
        int idx = i * 256 + t;
        int u = idx >> 6, h = idx & 63;
        int mm = (u * (2 * h + 1)) & 255;
        Dbf[u * S + h] = f2bf(cospif((float)mm * (1.0f / 128.0f)));
    }

    const int wv = t >> 6;
    const int l = t & 63;
    const int m = l & 15;
    const int q = l >> 4;
    const int arow = (16 * wv + m) * S + 8 * q;
    const int xh = t >> 4;
    const int xw0 = (4 * t) & 63;

    const int bc0 = blockIdx.x * 4;
    const float4* src4 = (const float4*)(ip + (size_t)bc0 * 4096);

    float4 xv[4];
#pragma unroll
    for (int i = 0; i < 4; ++i) xv[i] = src4[i * 256 + t];

    __syncthreads();  // D ready
    const bf16x8 da0 = *(const bf16x8*)&Dbf[arow];
    const bf16x8 da1 = *(const bf16x8*)&Dbf[arow + 32];

    for (int s = 0; s < 4; ++s) {
#pragma unroll
        for (int i = 0; i < 4; ++i) {
            ushort4 p;
            p.x = f2bf(xv[i].x); p.y = f2bf(xv[i].y);
            p.z = f2bf(xv[i].z); p.w = f2bf(xv[i].w);
            *(ushort4*)&Xbf[(16 * i + xh) * S + xw0] = p;
        }
        __syncthreads();  // X visible

        if (s < 3) {
            const float4* nsrc = src4 + (size_t)(s + 1) * 1024;
#pragma unroll
            for (int i = 0; i < 4; ++i) xv[i] = nsrc[i * 256 + t];
        }

        // Stage A: T = D @ X^T
        f32x4 acc[4];
#pragma unroll
        for (int tn = 0; tn < 4; ++tn) {
            const int brow = (16 * tn + m) * S + 8 * q;
            bf16x8 b0 = *(const bf16x8*)&Xbf[brow];
            bf16x8 b1 = *(const bf16x8*)&Xbf[brow + 32];
            f32x4 c = {0.0f, 0.0f, 0.0f, 0.0f};
            c = __builtin_amdgcn_mfma_f32_16x16x32_bf16(da0, b0, c, 0, 0, 0);
            c = __builtin_amdgcn_mfma_f32_16x16x32_bf16(da1, b1, c, 0, 0, 0);
            acc[tn] = c;
        }
#pragma unroll
        for (int tn = 0; tn < 4; ++tn)
#pragma unroll
            for (int reg = 0; reg < 4; ++reg)
                Tbf[(16 * wv + 4 * q + reg) * S + 16 * tn + m] = f2bf(acc[tn][reg]);
        __syncthreads();  // T visible

        // Stage B: Y' = T @ D^T, fused max
        bf16x8 ta0 = *(const bf16x8*)&Tbf[arow];
        bf16x8 ta1 = *(const bf16x8*)&Tbf[arow + 32];
        float mx = -3.4e38f;
#pragma unroll
        for (int tn = 0; tn < 4; ++tn) {
            const int brow = (16 * tn + m) * S + 8 * q;
            bf16x8 b0 = *(const bf16x8*)&Dbf[brow];
            bf16x8 b1 = *(const bf16x8*)&Dbf[brow + 32];
            f32x4 c = {0.0f, 0.0f, 0.0f, 0.0f};
            c = __builtin_amdgcn_mfma_f32_16x16x32_bf16(ta0, b0, c, 0, 0, 0);
            c = __builtin_amdgcn_mfma_f32_16x16x32_bf16(ta1, b1, c, 0, 0, 0);
            mx = fmaxf(mx, fmaxf(fmaxf(c[0], c[1]), fmaxf(c[2], c[3])));
        }

#pragma unroll
        for (int off = 32; off > 0; off >>= 1) mx = fmaxf(mx, __shfl_down(mx, off, 64));
        if (l == 0) red[wv] = mx;
        __syncthreads();
        if (t == 0) {
            float M = fmaxf(fmaxf(red[0], red[1]), fmaxf(red[2], red[3]));
            top1[bc0 + s] = M * (1.0f / 4096.0f);
        }
    }
}

// 4 slices per block (same batch b). Bulk loads issued first; MLP computed in
// their shadow; nontemporal stores avoid write-allocate/RFO.
__global__ __launch_bounds__(256, 4) void scale_kernel(const float* __restrict__ ip,
                                                       const float* __restrict__ top1,
                                                       const float* __restrict__ w1,
                                                       const float* __restrict__ w2,
                                                       float* __restrict__ out) {
    __shared__ float h_s[16];
    __shared__ float w_s[4];
    const int t = threadIdx.x;
    const int bc0 = blockIdx.x * 4;
    const int b = bc0 >> 8, c0 = bc0 & 255;

    const f32x4* ip4 = (const f32x4*)ip + (size_t)bc0 * 1024;
    f32x4* out4 = (f32x4*)out + (size_t)bc0 * 1024;

    // ---- Issue MLP's small loads, then the 16 bulk loads (all independent) ----
    const int j = t >> 4, i = t & 15;
    float tvals[16], wvals[16];
#pragma unroll
    for (int k = 0; k < 16; ++k) {
        int cc = i + 16 * k;
        tvals[k] = top1[b * 256 + cc];
        wvals[k] = w1[cc * 16 + j];
    }
    f32x4 v[16];
#pragma unroll
    for (int s = 0; s < 4; ++s)
#pragma unroll
        for (int k = 0; k < 4; ++k) v[s * 4 + k] = ip4[(size_t)s * 1024 + k * 256 + t];

    // ---- MLP under the bulk loads' shadow ----
    float partial = 0.0f;
#pragma unroll
    for (int k = 0; k < 16; ++k) partial = fmaf(tvals[k], wvals[k], partial);
#pragma unroll
    for (int off = 8; off > 0; off >>= 1) partial += __shfl_xor(partial, off, 16);
    if (i == 0) h_s[j] = fmaxf(partial, 0.0f);
    __syncthreads();

    if (t < 64) {  // 4 channels x 16 lanes
        const int sc = t >> 4, jj = t & 15;
        float p2 = h_s[jj] * w2[jj * 256 + (c0 + sc)];
#pragma unroll
        for (int off = 8; off > 0; off >>= 1) p2 += __shfl_xor(p2, off, 16);
        if (jj == 0) w_s[sc] = 1.0f / (1.0f + __expf(-p2));
    }
    __syncthreads();

    // ---- Scale + nontemporal store ----
#pragma unroll
    for (int s = 0; s < 4; ++s) {
        const float wt = w_s[s];
#pragma unroll
        for (int k = 0; k < 4; ++k) {
            f32x4 r = v[s * 4 + k] * wt;
            __builtin_nontemporal_store(r, &out4[(size_t)s * 1024 + k * 256 + t]);
        }
    }
}

extern "C" void kernel_launch(void* const* d_in, const int* in_sizes, int n_in,
                              void* d_out, int out_size, void* d_ws, size_t ws_size,
                              hipStream_t stream) {
    const float* ip = (const float*)d_in[0];   // [16,256,64,64]
    const float* w1 = (const float*)d_in[1];   // [256,16]
    const float* w2 = (const float*)d_in[2];   // [16,256]
    float* out = (float*)d_out;
    float* top1 = (float*)d_ws;                // 4096 floats

    dct_max_kernel<<<1024, 256, 0, stream>>>(ip, top1);
    scale_kernel<<<1024, 256, 0, stream>>>(ip, top1, w1, w2, out);
}